// Round 6
// baseline (6269.032 us; speedup 1.0000x reference)
//
#include <hip/hip_runtime.h>
#include <math.h>

#define TAGS 9

static __device__ __forceinline__ float sigmoidf_(float x) {
  return 1.0f / (1.0f + expf(-x));
}

// MALL-coherent (cross-XCD) plain data movement (validated rounds 2-5).
__device__ __forceinline__ float4 ld4_sc(const float* p) {
  float4 r;
  asm volatile("global_load_dwordx4 %0, %1, off sc0 sc1" : "=v"(r) : "v"(p) : "memory");
  return r;
}
__device__ __forceinline__ void st1_sc(float* p, float v) {
  asm volatile("global_store_dword %0, %1, off sc0 sc1" :: "v"(p), "v"(v) : "memory");
}
__device__ __forceinline__ void sti_sc(int* p, int v) {
  asm volatile("global_store_dword %0, %1, off sc0 sc1" :: "v"(p), "v"(v) : "memory");
}
__device__ __forceinline__ int ldi_sc(const int* p) {
  int r;
  asm volatile("global_load_dword %0, %1, off sc0 sc1" : "=v"(r) : "v"(p) : "memory");
  return r;
}
__device__ __forceinline__ void waitcnt0() {
  asm volatile("s_waitcnt vmcnt(0)" ::: "memory");
}
__device__ __forceinline__ bool valid4(float4 v) {
  return fabsf(v.x) < 1.5f && fabsf(v.y) < 1.5f && fabsf(v.z) < 1.5f && fabsf(v.w) < 1.5f;
}

// ---------------- pack Whh into per-WG scalar-streamable layout ----------------
// wPack[L][wg][k][rr]: wg = d*64+ug (4 units), rr = gate*4 + uo. 2*128*256*16 floats.
__global__ void k_pack_w(const float* __restrict__ whh, float* __restrict__ wPack) {
  int i = blockIdx.x * 256 + threadIdx.x;       // < 1048576
  int rr = i & 15;
  int k = (i >> 4) & 255;
  int wg = (i >> 12) & 127;
  int L = i >> 19;
  int d = wg >> 6, ug = wg & 63;
  int row = d * 1024 + (rr >> 2) * 256 + ug * 4 + (rr & 3);
  wPack[i] = whh[(size_t)L * 524288 + (size_t)row * 256 + k];
}

// owT[ch][12]: transposed out_w (padded stride 12 for aligned x4/x4/x1 scalar loads)
__global__ void k_pack_ow(const float* __restrict__ out_w, float* __restrict__ owT) {
  int i = blockIdx.x * 256 + threadIdx.x;       // < 4608
  int tag = i % 9, ch = i / 9;
  owT[ch * 12 + tag] = out_w[tag * 512 + ch];
}

// ---------------- fused gather + transpose: seqT[ch][tb] = table[x[tb]][ch] ----------------
__global__ __launch_bounds__(256, 1)
void k_gatherT(const int* __restrict__ x, const float* __restrict__ table,
               float* __restrict__ seqT) {
  __shared__ float tile[64 * 513];
  __shared__ int x_s[64];
  int wg = blockIdx.x;           // 256 WGs x 64 tb
  int tid = threadIdx.x;
  int tb0 = wg * 64;
  if (tid < 64) x_s[tid] = x[tb0 + tid];
  __syncthreads();
#pragma unroll
  for (int i = 0; i < 32; i++) {
    int idx = tid + i * 256;     // float4 index over [64 rows][128 f4]
    int r = idx >> 7, c4 = (idx & 127) * 4;
    float4 v = *(const float4*)&table[(size_t)x_s[r] * 512 + c4];
    float* tp = &tile[r * 513 + c4];
    tp[0] = v.x; tp[1] = v.y; tp[2] = v.z; tp[3] = v.w;
  }
  __syncthreads();
#pragma unroll
  for (int i = 0; i < 128; i++) {
    int j = tid + i * 256;       // over [512 ch][64 b]
    int ch = j >> 6, b = j & 63;
    seqT[(size_t)ch * 16384 + tb0 + b] = tile[b * 513 + ch];
  }
}

// ---------------- gates GEMM: gatesT[t][m][b] = sum_k A[m][k]*seqT[k][t*64+b] + biases ----------------
__global__ __launch_bounds__(256, 2)
void k_gemm_gates(const float* __restrict__ A, const float* __restrict__ seqT,
                  const float* __restrict__ bias1, const float* __restrict__ bias2,
                  float* __restrict__ gatesT) {
  __shared__ float As[16][132];
  __shared__ float Bs[16][132];
  int tid = threadIdx.x;
  int tx = tid & 15, ty = tid >> 4;
  int n0 = blockIdx.x * 128, m0 = blockIdx.y * 128;
  int lr = tid >> 2;
  int lk = (tid & 3) * 4;
  int bkk = tid >> 4, bn8 = (tid & 15) * 8;
  float acc[8][8];
#pragma unroll
  for (int i = 0; i < 8; i++)
#pragma unroll
    for (int j = 0; j < 8; j++) acc[i][j] = 0.f;
  const float* Ab = A + (size_t)m0 * 512;
  for (int k0 = 0; k0 < 512; k0 += 16) {
    float4 a0 = *(const float4*)&Ab[(size_t)lr * 512 + k0 + lk];
    float4 a1 = *(const float4*)&Ab[(size_t)(lr + 64) * 512 + k0 + lk];
    const float* Bp = seqT + (size_t)(k0 + bkk) * 16384 + n0 + bn8;
    float4 b0 = *(const float4*)Bp;
    float4 b1 = *(const float4*)(Bp + 4);
    __syncthreads();
    As[lk + 0][lr] = a0.x; As[lk + 1][lr] = a0.y; As[lk + 2][lr] = a0.z; As[lk + 3][lr] = a0.w;
    As[lk + 0][lr + 64] = a1.x; As[lk + 1][lr + 64] = a1.y; As[lk + 2][lr + 64] = a1.z; As[lk + 3][lr + 64] = a1.w;
    *(float4*)&Bs[bkk][bn8] = b0;
    *(float4*)&Bs[bkk][bn8 + 4] = b1;
    __syncthreads();
#pragma unroll
    for (int kk = 0; kk < 16; kk++) {
      float4 av0 = *(const float4*)&As[kk][ty * 4];
      float4 av1 = *(const float4*)&As[kk][ty * 4 + 64];
      float4 bv0 = *(const float4*)&Bs[kk][tx * 4];
      float4 bv1 = *(const float4*)&Bs[kk][tx * 4 + 64];
      float am[8] = {av0.x, av0.y, av0.z, av0.w, av1.x, av1.y, av1.z, av1.w};
      float bn[8] = {bv0.x, bv0.y, bv0.z, bv0.w, bv1.x, bv1.y, bv1.z, bv1.w};
#pragma unroll
      for (int i = 0; i < 8; i++)
#pragma unroll
        for (int j = 0; j < 8; j++) acc[i][j] += am[i] * bn[j];
    }
  }
  int t0 = n0 >> 6;
#pragma unroll
  for (int i = 0; i < 8; i++) {
    int m = m0 + ((i < 4) ? (ty * 4 + i) : (64 + ty * 4 + (i - 4)));
    float bs = bias1[m] + bias2[m];
    float4 o0 = {acc[i][0] + bs, acc[i][1] + bs, acc[i][2] + bs, acc[i][3] + bs};
    float4 o1 = {acc[i][4] + bs, acc[i][5] + bs, acc[i][6] + bs, acc[i][7] + bs};
    *(float4*)&gatesT[((size_t)t0 * 2048 + m) * 64 + tx * 4] = o0;
    *(float4*)&gatesT[((size_t)(t0 + 1) * 2048 + m) * 64 + tx * 4] = o1;
  }
}

// ---------------- LSTM recurrence ----------------
// 128 WGs x 512 thr. WG=(d, 4 units). Rotating sentinel'd h slots [t][d][b][u]:
// publish = sc stores, NO drain wait; flag per producer in its own 64B line;
// consumers flag-poll (padded, sc) then bulk-load h with NORMAL x4 loads (virgin
// lines -> per-XCD L2 dedup), verify against sentinel (|v|<1.5), sc-patch rares.
__global__ __launch_bounds__(512, 1)
void k_lstm_rec(const float* __restrict__ gatesT,   // [256][2048][64]
                const float* __restrict__ wPack,    // [128][256][16] this layer
                float* __restrict__ seqT_out,       // [512][16384]
                float* __restrict__ hrot,           // [256 slots][2 d][64 b][256 u]
                int* __restrict__ flags,            // [2 d][256 step][64 wg][16 pad]
                int layer) {
  __shared__ float p_s[8 * 16 * 64];
  int wg = blockIdx.x, tid = threadIdx.x;
  int d = wg >> 6;
  int u0 = (wg & 63) * 4;
  int b = tid & 63;
  int kq = __builtin_amdgcn_readfirstlane(tid >> 6);   // wave index 0..7
  int uo = tid >> 6;                                   // pointwise role (tid<256)
  const float4* wp4 = (const float4*)(wPack + ((size_t)wg * 256 + kq * 32) * 16);
  float c = 0.f;

  for (int tt = 0; tt < 256; ++tt) {
    int t = d ? 255 - tt : tt;
    // prefetch this step's input-gate values (normal cached loads, consumed post-S1)
    float gin0 = 0.f, gin1 = 0.f, gin2 = 0.f, gin3 = 0.f;
    if (tid < 256) {
      const float* gp = gatesT + ((size_t)t * 2048 + d * 1024 + u0 + uo) * 64 + b;
      gin0 = gp[0 * 16384];
      gin1 = gp[1 * 16384];
      gin2 = gp[2 * 16384];
      gin3 = gp[3 * 16384];
    }
    // bulk h load: lane b reads 32 consecutive u (8 x4, 128B contiguous per lane)
    const float* hp = hrot + (((size_t)tt * 2 + d) * 64 + b) * 256 + kq * 32;
    const float4* hp4 = (const float4*)hp;
    float4 hv[8];
#pragma unroll
    for (int j = 0; j < 8; j++) hv[j] = hp4[j];
    // verify vs sentinel; patch stale chunks through MALL (flag overtook data)
    unsigned bad = 0;
#pragma unroll
    for (int j = 0; j < 8; j++) bad |= valid4(hv[j]) ? 0u : (1u << j);
    while (__any(bad)) {
#pragma unroll
      for (int j = 0; j < 8; j++) if (bad & (1u << j)) hv[j] = ld4_sc(hp + j * 4);
      waitcnt0();
#pragma unroll
      for (int j = 0; j < 8; j++) if (valid4(hv[j])) bad &= ~(1u << j);
      if (__any(bad)) __builtin_amdgcn_s_sleep(1);
    }
    // GEMV: acc[rr] += wPack[k][rr] * h[k]; w chunks wave-uniform (scalar pipe)
    float acc[16];
#pragma unroll
    for (int r = 0; r < 16; r++) acc[r] = 0.f;
#pragma unroll 2
    for (int jj = 0; jj < 8; jj++) {
      float hq[4] = {hv[jj].x, hv[jj].y, hv[jj].z, hv[jj].w};
#pragma unroll
      for (int cc = 0; cc < 4; cc++) {
        int j = jj * 4 + cc;
        float hj = hq[cc];
        float4 w0 = wp4[j * 4 + 0];
        float4 w1 = wp4[j * 4 + 1];
        float4 w2 = wp4[j * 4 + 2];
        float4 w3 = wp4[j * 4 + 3];
        acc[0] += w0.x * hj;  acc[1] += w0.y * hj;  acc[2] += w0.z * hj;  acc[3] += w0.w * hj;
        acc[4] += w1.x * hj;  acc[5] += w1.y * hj;  acc[6] += w1.z * hj;  acc[7] += w1.w * hj;
        acc[8] += w2.x * hj;  acc[9] += w2.y * hj;  acc[10] += w2.z * hj; acc[11] += w2.w * hj;
        acc[12] += w3.x * hj; acc[13] += w3.y * hj; acc[14] += w3.z * hj; acc[15] += w3.w * hj;
      }
    }
#pragma unroll
    for (int r = 0; r < 16; r++) p_s[(kq * 16 + r) * 64 + b] = acc[r];
    __syncthreads();
    // combine + pointwise + publish (tid<256; unit u0+uo, batch b)
    if (tid < 256) {
      float gv[4] = {gin0, gin1, gin2, gin3};
#pragma unroll
      for (int g = 0; g < 4; g++) {
        int rr = g * 4 + uo;
        float s = gv[g];
#pragma unroll
        for (int q = 0; q < 8; q++) s += p_s[(q * 16 + rr) * 64 + b];
        gv[g] = s;
      }
      c = sigmoidf_(gv[1]) * c + sigmoidf_(gv[0]) * tanhf(gv[2]);
      float h = sigmoidf_(gv[3]) * tanhf(c);
      if (tt < 255) {
        // publish first (critical path), no drain wait — sentinel covers the race
        st1_sc(hrot + (((size_t)(tt + 1) * 2 + d) * 64 + b) * 256 + u0 + uo, h);
      }
      seqT_out[(size_t)(d * 256 + u0 + uo) * 16384 + t * 64 + b] = h;
    }
    if (tt < 255) {
      __syncthreads();       // all publishes ISSUED (order only; no drain)
      int* fbase = flags + ((size_t)d * 256 + tt) * 1024;   // 64 wg x 16-int pad
      int expect = layer * 256 + tt + 1;
      if (tid == 0) sti_sc(fbase + (wg & 63) * 16, expect);
      if (tid < 64) {
        while (true) {
          int v = ldi_sc(fbase + tid * 16);
          waitcnt0();
          if (__all(v == expect)) break;
          __builtin_amdgcn_s_sleep(1);
        }
      }
      __syncthreads();
    }
  }
}

// ---------------- emissions: em[tb][tag] = sum_ch seqT[ch][tb]*owT[ch][tag] + out_b ----------------
__global__ __launch_bounds__(256, 4)
void k_emis(const float* __restrict__ seqT, const float* __restrict__ owT,
            const float* __restrict__ out_b, float* __restrict__ em) {
  int tb = blockIdx.x * 256 + threadIdx.x;   // 64 WGs
  float p[TAGS];
#pragma unroll
  for (int t = 0; t < TAGS; t++) p[t] = 0.f;
  for (int ch = 0; ch < 512; ch++) {
    float sv = seqT[(size_t)ch * 16384 + tb];
    const float4* o4 = (const float4*)(owT + ch * 12);   // wave-uniform -> scalar loads
    float4 oa = o4[0], ob = o4[1];
    float oc = owT[ch * 12 + 8];
    p[0] += sv * oa.x; p[1] += sv * oa.y; p[2] += sv * oa.z; p[3] += sv * oa.w;
    p[4] += sv * ob.x; p[5] += sv * ob.y; p[6] += sv * ob.z; p[7] += sv * ob.w;
    p[8] += sv * oc;
  }
#pragma unroll
  for (int t = 0; t < TAGS; t++) em[(size_t)tb * TAGS + t] = p[t] + out_b[t];
}

// ---------------- Viterbi: one wave per batch ----------------
__global__ void k_viterbi(const float* __restrict__ em, const float* __restrict__ start_t,
                          const float* __restrict__ end_t, const float* __restrict__ trans,
                          float* __restrict__ out) {
  int b = blockIdx.x;
  int lane = threadIdx.x;
  __shared__ unsigned char hist[255 * TAGS];
  float tin[TAGS];
#pragma unroll
  for (int p = 0; p < TAGS; p++) tin[p] = (lane < TAGS) ? trans[p * TAGS + lane] : 0.f;
  float score = -1e30f;
  if (lane < TAGS) score = start_t[lane] + em[(size_t)b * TAGS + lane];
  for (int t = 1; t < 256; t++) {
    float best = -1e30f; int bp = 0;
#pragma unroll
    for (int p = 0; p < TAGS; p++) {
      float v = __shfl(score, p, 64) + tin[p];
      if (v > best) { best = v; bp = p; }   // strict > + ascending p == first-max (jnp.argmax)
    }
    if (lane < TAGS) {
      score = best + em[(size_t)(t * 64 + b) * TAGS + lane];
      hist[(t - 1) * TAGS + lane] = (unsigned char)bp;
    }
  }
  float fin = (lane < TAGS) ? (score + end_t[lane]) : -1e30f;
  float bsc = -1e30f; int bl = 0;
#pragma unroll
  for (int p = 0; p < TAGS; p++) {
    float v = __shfl(fin, p, 64);
    if (v > bsc) { bsc = v; bl = p; }
  }
  __syncthreads();
  if (lane == 0) {
    out[(size_t)16384 + b] = bsc;
    int tag = bl;
    out[(size_t)b * 256 + 255] = (float)tag;
    for (int t = 254; t >= 0; t--) {
      tag = hist[t * TAGS + tag];
      out[(size_t)b * 256 + t] = (float)tag;
    }
  }
}

extern "C" void kernel_launch(void* const* d_in, const int* in_sizes, int n_in,
                              void* d_out, int out_size, void* d_ws, size_t ws_size,
                              hipStream_t stream) {
  const int*   x       = (const int*)d_in[0];
  const float* table   = (const float*)d_in[1];
  const float* w_ih    = (const float*)d_in[2];   // [2][2][1024][512]
  const float* w_hh    = (const float*)d_in[3];   // [2][2][1024][256]
  const float* b_ih    = (const float*)d_in[4];
  const float* b_hh    = (const float*)d_in[5];
  const float* out_w   = (const float*)d_in[6];
  const float* out_b   = (const float*)d_in[7];
  const float* start_t = (const float*)d_in[8];
  const float* end_t   = (const float*)d_in[9];
  const float* trans   = (const float*)d_in[10];
  float* out = (float*)d_out;
  float* ws = (float*)d_ws;

  float* seqT0  = ws;                       // 8,388,608  (embeds -> layer-1 output)
  float* seqT1  = seqT0 + 8388608;          // 8,388,608  (layer-0 output)
  float* gatesT = seqT1 + 8388608;          // 33,554,432
  float* em     = gatesT;                   // overlays gatesT (dead by k_emis time)
  float* hrot   = gatesT + 33554432;        // 256*2*64*256 = 8,388,608 rotating h slots
  float* wPack  = hrot + 8388608;           // 1,048,576 ([2 layers][128][256][16])
  float* owT    = wPack + 1048576;          // 6,144
  int*   flags  = (int*)(owT + 6144);       // 524,288 ints ([2 d][256][64][16])
  // total ~242 MB

  // sentinel-init h slots: 0x7F7F7F7F = 3.39e38 (|h| < 1 always -> distinguishable)
  hipMemsetAsync(hrot, 0x7F, (size_t)8388608 * 4, stream);
  hipMemsetAsync(hrot, 0, (size_t)32768 * 4, stream);          // slot 0 (h0 = zeros)

  k_pack_w<<<4096, 256, 0, stream>>>(w_hh, wPack);
  k_pack_ow<<<18, 256, 0, stream>>>(out_w, owT);
  k_gatherT<<<256, 256, 0, stream>>>(x, table, seqT0);

  dim3 gg(128, 16);
  k_gemm_gates<<<gg, 256, 0, stream>>>(w_ih, seqT0, b_ih, b_hh, gatesT);
  k_lstm_rec<<<128, 512, 0, stream>>>(gatesT, wPack, seqT1, hrot, flags, 0);
  // re-sentinel slots 1..255 for layer 1 (slot 0 remains zeros)
  hipMemsetAsync(hrot + 32768, 0x7F, (size_t)(8388608 - 32768) * 4, stream);
  k_gemm_gates<<<gg, 256, 0, stream>>>(w_ih + 1048576, seqT1, b_ih + 2048, b_hh + 2048, gatesT);
  k_lstm_rec<<<128, 512, 0, stream>>>(gatesT, wPack + 524288, seqT0, hrot, flags, 1);
  k_emis<<<64, 256, 0, stream>>>(seqT0, owT, out_b, em);
  k_viterbi<<<64, 64, 0, stream>>>(em, start_t, end_t, trans, out);
}